// Round 1
// baseline (1112.960 us; speedup 1.0000x reference)
//
#include <hip/hip_runtime.h>
#include <hip/hip_bf16.h>

typedef unsigned int uint32;
typedef unsigned short ushort16;

#define BB 8
#define CC 256
#define TT 4096
#define NN (BB*TT)          // 32768 rows
#define KK 1024
#define RT 16               // rows per block
#define NBLK (NN/RT)        // 2048 blocks

#define OUT_PREC ((size_t)BB*CC*TT)                 // 8388608
#define OUT_PROB (OUT_PREC + 1)                     // 8388609
#define OUT_LOGPROB (OUT_PROB + (size_t)NN*KK)
#define OUT_MEANPROB (OUT_LOGPROB + (size_t)NN*KK)

__device__ __forceinline__ ushort16 f2bf(float f) {
    uint32 x = __float_as_uint(f);
    x += 0x7fffu + ((x >> 16) & 1u);   // RNE; inputs are probabilities, no NaN/Inf
    return (ushort16)(x >> 16);
}

// -------- prep: book row norms, zero mean_prob, write precision_q --------
__global__ void prep_kernel(const float* __restrict__ book,
                            const float* __restrict__ lpq,
                            float* __restrict__ enorm,
                            float* __restrict__ out) {
    int k = blockIdx.x * blockDim.x + threadIdx.x;   // grid 4 x 256 = 1024
    const float4* bp = (const float4*)(book + (size_t)k * CC);
    float s = 0.f;
#pragma unroll 8
    for (int i = 0; i < CC/4; ++i) {
        float4 v = bp[i];
        s = fmaf(v.x, v.x, s); s = fmaf(v.y, v.y, s);
        s = fmaf(v.z, v.z, s); s = fmaf(v.w, v.w, s);
    }
    enorm[k] = s;
    out[OUT_MEANPROB + k] = 0.f;
    if (k == 0) {
        float pq = 1.f + expf(lpq[0]);
        out[OUT_PREC] = 0.5f / fmaxf(pq, 1e-10f);
    }
}

// -------- main fused kernel --------
__global__ __launch_bounds__(256, 2)
void gvq_main(const float* __restrict__ z, const float* __restrict__ book,
              const float* __restrict__ lpq, const float* __restrict__ u,
              const float* __restrict__ enorm, float* __restrict__ out,
              float* __restrict__ part) {
    __shared__ float ztile[RT][CC];        // 16 KB; reused for z_q staging
    __shared__ ushort16 enc_s[RT][KK];     // 32 KB (bf16 encodings)
    __shared__ float red_s[4][RT];
    __shared__ float znorm_s[RT];

    const int tid  = threadIdx.x;
    const int lane = tid & 63;
    const int wid  = tid >> 6;
    const int n0   = blockIdx.x * RT;      // 4096 % 16 == 0: tile never crosses batch
    const int bb   = n0 / TT;
    const int t0   = n0 % TT;

    const float prec = 0.5f / fmaxf(1.f + expf(lpq[0]), 1e-10f);

    // ---- phase 1: z tile load (thread = channel c, 16 t's contiguous = 64B/lane)
    {
        const float4* zp = (const float4*)(z + ((size_t)bb * CC + tid) * TT + t0);
        float4 a0 = zp[0], a1 = zp[1], a2 = zp[2], a3 = zp[3];
        ztile[0][tid]  = a0.x; ztile[1][tid]  = a0.y; ztile[2][tid]  = a0.z; ztile[3][tid]  = a0.w;
        ztile[4][tid]  = a1.x; ztile[5][tid]  = a1.y; ztile[6][tid]  = a1.z; ztile[7][tid]  = a1.w;
        ztile[8][tid]  = a2.x; ztile[9][tid]  = a2.y; ztile[10][tid] = a2.z; ztile[11][tid] = a2.w;
        ztile[12][tid] = a3.x; ztile[13][tid] = a3.y; ztile[14][tid] = a3.z; ztile[15][tid] = a3.w;
    }
    __syncthreads();

    // ---- phase 1b: row norms (wave wid handles rows wid*4..+3)
#pragma unroll
    for (int rr = 0; rr < 4; ++rr) {
        int r = (wid << 2) + rr;
        float4 v = *(const float4*)&ztile[r][lane << 2];
        float s = fmaf(v.x, v.x, fmaf(v.y, v.y, fmaf(v.z, v.z, v.w * v.w)));
#pragma unroll
        for (int off = 32; off > 0; off >>= 1) s += __shfl_xor(s, off);
        if (lane == 0) znorm_s[r] = s;
    }
    __syncthreads();

    // ---- GEMM1: logits[r][k], thread owns k = tid + {0,256,512,768}
    float acc[RT][4];
#pragma unroll
    for (int r = 0; r < RT; ++r)
#pragma unroll
        for (int i = 0; i < 4; ++i) acc[r][i] = 0.f;

#pragma unroll 1
    for (int c0 = 0; c0 < CC; c0 += 16) {
        float4 bk[4][4];
#pragma unroll
        for (int i = 0; i < 4; ++i) {
            const float4* bp = (const float4*)(book + (size_t)(tid + (i << 8)) * CC + c0);
            bk[i][0] = bp[0]; bk[i][1] = bp[1]; bk[i][2] = bp[2]; bk[i][3] = bp[3];
        }
#pragma unroll
        for (int r = 0; r < RT; ++r) {
            float4 z0 = *(const float4*)&ztile[r][c0];
            float4 z1 = *(const float4*)&ztile[r][c0 + 4];
            float4 z2 = *(const float4*)&ztile[r][c0 + 8];
            float4 z3 = *(const float4*)&ztile[r][c0 + 12];
#pragma unroll
            for (int i = 0; i < 4; ++i) {
                float s = acc[r][i];
                s = fmaf(z0.x, bk[i][0].x, s); s = fmaf(z0.y, bk[i][0].y, s);
                s = fmaf(z0.z, bk[i][0].z, s); s = fmaf(z0.w, bk[i][0].w, s);
                s = fmaf(z1.x, bk[i][1].x, s); s = fmaf(z1.y, bk[i][1].y, s);
                s = fmaf(z1.z, bk[i][1].z, s); s = fmaf(z1.w, bk[i][1].w, s);
                s = fmaf(z2.x, bk[i][2].x, s); s = fmaf(z2.y, bk[i][2].y, s);
                s = fmaf(z2.z, bk[i][2].z, s); s = fmaf(z2.w, bk[i][2].w, s);
                s = fmaf(z3.x, bk[i][3].x, s); s = fmaf(z3.y, bk[i][3].y, s);
                s = fmaf(z3.z, bk[i][3].z, s); s = fmaf(z3.w, bk[i][3].w, s);
                acc[r][i] = s;
            }
        }
    }

    // ---- logits = (2*dot - ||z||^2 - ||e||^2) * prec
    float en[4];
#pragma unroll
    for (int i = 0; i < 4; ++i) en[i] = enorm[tid + (i << 8)];
#pragma unroll
    for (int r = 0; r < RT; ++r) {
        float zn = znorm_s[r];
#pragma unroll
        for (int i = 0; i < 4; ++i)
            acc[r][i] = (2.f * acc[r][i] - zn - en[i]) * prec;
    }

    // ---- softmax 1 (prob / log_prob)
    float rowmax[RT], rowsum[RT];
#pragma unroll
    for (int r = 0; r < RT; ++r) {
        float m = fmaxf(fmaxf(acc[r][0], acc[r][1]), fmaxf(acc[r][2], acc[r][3]));
#pragma unroll
        for (int off = 32; off > 0; off >>= 1) m = fmaxf(m, __shfl_xor(m, off));
        if (lane == 0) red_s[wid][r] = m;
    }
    __syncthreads();
#pragma unroll
    for (int r = 0; r < RT; ++r)
        rowmax[r] = fmaxf(fmaxf(red_s[0][r], red_s[1][r]), fmaxf(red_s[2][r], red_s[3][r]));
    __syncthreads();
#pragma unroll
    for (int r = 0; r < RT; ++r) {
        float s = __expf(acc[r][0] - rowmax[r]) + __expf(acc[r][1] - rowmax[r])
                + __expf(acc[r][2] - rowmax[r]) + __expf(acc[r][3] - rowmax[r]);
#pragma unroll
        for (int off = 32; off > 0; off >>= 1) s += __shfl_xor(s, off);
        if (lane == 0) red_s[wid][r] = s;
    }
    __syncthreads();
#pragma unroll
    for (int r = 0; r < RT; ++r)
        rowsum[r] = red_s[0][r] + red_s[1][r] + red_s[2][r] + red_s[3][r];

    float mp[4] = {0.f, 0.f, 0.f, 0.f};
    {
        float* prob_out = out + OUT_PROB;
        float* lp_out   = out + OUT_LOGPROB;
#pragma unroll
        for (int r = 0; r < RT; ++r) {
            float logs = __logf(rowsum[r]);
            size_t base = (size_t)(n0 + r) * KK + tid;
#pragma unroll
            for (int i = 0; i < 4; ++i) {
                float lp = (acc[r][i] - rowmax[r]) - logs;
                float p  = __expf(lp);
                prob_out[base + (i << 8)] = p;
                lp_out[base + (i << 8)]   = lp;
                mp[i] += p;
            }
        }
    }
    if (part != nullptr) {
#pragma unroll
        for (int i = 0; i < 4; ++i)
            part[(size_t)blockIdx.x * KK + tid + (i << 8)] = mp[i];
    } else {
#pragma unroll
        for (int i = 0; i < 4; ++i)
            atomicAdd(out + OUT_MEANPROB + tid + (i << 8), mp[i] * (1.f / NN));
    }

    // ---- Gumbel + softmax 2 (encodings), temperature 0.5 => *2
#pragma unroll
    for (int r = 0; r < RT; ++r) {
        size_t base = (size_t)(n0 + r) * KK + tid;
#pragma unroll
        for (int i = 0; i < 4; ++i) {
            float uu = u[base + (i << 8)];
            float g  = -__logf(-__logf(uu + 1e-10f) + 1e-10f);
            acc[r][i] = (acc[r][i] + g) * 2.0f;
        }
    }
    __syncthreads();   // guard red_s reuse
#pragma unroll
    for (int r = 0; r < RT; ++r) {
        float m = fmaxf(fmaxf(acc[r][0], acc[r][1]), fmaxf(acc[r][2], acc[r][3]));
#pragma unroll
        for (int off = 32; off > 0; off >>= 1) m = fmaxf(m, __shfl_xor(m, off));
        if (lane == 0) red_s[wid][r] = m;
    }
    __syncthreads();
#pragma unroll
    for (int r = 0; r < RT; ++r)
        rowmax[r] = fmaxf(fmaxf(red_s[0][r], red_s[1][r]), fmaxf(red_s[2][r], red_s[3][r]));
    __syncthreads();
#pragma unroll
    for (int r = 0; r < RT; ++r) {
        float s = __expf(acc[r][0] - rowmax[r]) + __expf(acc[r][1] - rowmax[r])
                + __expf(acc[r][2] - rowmax[r]) + __expf(acc[r][3] - rowmax[r]);
#pragma unroll
        for (int off = 32; off > 0; off >>= 1) s += __shfl_xor(s, off);
        if (lane == 0) red_s[wid][r] = s;
    }
    __syncthreads();
#pragma unroll
    for (int r = 0; r < RT; ++r)
        rowsum[r] = red_s[0][r] + red_s[1][r] + red_s[2][r] + red_s[3][r];

#pragma unroll
    for (int r = 0; r < RT; ++r) {
        float inv = 1.0f / rowsum[r];
#pragma unroll
        for (int i = 0; i < 4; ++i) {
            float e = __expf(acc[r][i] - rowmax[r]) * inv;
            enc_s[r][tid + (i << 8)] = f2bf(e);
        }
    }
    __syncthreads();

    // ---- GEMM2: z_q[r][c] = sum_k enc[k]*book[k][c]
    // wave wid -> rows wid*4..+3 ; lane -> c = lane*4..+3 (book row loads fully coalesced)
    float accz[4][4];
#pragma unroll
    for (int rr = 0; rr < 4; ++rr)
#pragma unroll
        for (int cc = 0; cc < 4; ++cc) accz[rr][cc] = 0.f;

    const int c0g = lane << 2;
    const int r0g = wid << 2;
#pragma unroll 1
    for (int k0 = 0; k0 < KK; k0 += 8) {
        float4 bk[8];
#pragma unroll
        for (int kk = 0; kk < 8; ++kk)
            bk[kk] = *(const float4*)(book + (size_t)(k0 + kk) * CC + c0g);
#pragma unroll
        for (int rr = 0; rr < 4; ++rr) {
            uint4 ee = *(const uint4*)&enc_s[r0g + rr][k0];
            float e0 = __uint_as_float(ee.x << 16);
            float e1 = __uint_as_float(ee.x & 0xffff0000u);
            float e2 = __uint_as_float(ee.y << 16);
            float e3 = __uint_as_float(ee.y & 0xffff0000u);
            float e4 = __uint_as_float(ee.z << 16);
            float e5 = __uint_as_float(ee.z & 0xffff0000u);
            float e6 = __uint_as_float(ee.w << 16);
            float e7 = __uint_as_float(ee.w & 0xffff0000u);
            float sx = accz[rr][0], sy = accz[rr][1], sz = accz[rr][2], sw = accz[rr][3];
            sx = fmaf(e0, bk[0].x, sx); sy = fmaf(e0, bk[0].y, sy); sz = fmaf(e0, bk[0].z, sz); sw = fmaf(e0, bk[0].w, sw);
            sx = fmaf(e1, bk[1].x, sx); sy = fmaf(e1, bk[1].y, sy); sz = fmaf(e1, bk[1].z, sz); sw = fmaf(e1, bk[1].w, sw);
            sx = fmaf(e2, bk[2].x, sx); sy = fmaf(e2, bk[2].y, sy); sz = fmaf(e2, bk[2].z, sz); sw = fmaf(e2, bk[2].w, sw);
            sx = fmaf(e3, bk[3].x, sx); sy = fmaf(e3, bk[3].y, sy); sz = fmaf(e3, bk[3].z, sz); sw = fmaf(e3, bk[3].w, sw);
            sx = fmaf(e4, bk[4].x, sx); sy = fmaf(e4, bk[4].y, sy); sz = fmaf(e4, bk[4].z, sz); sw = fmaf(e4, bk[4].w, sw);
            sx = fmaf(e5, bk[5].x, sx); sy = fmaf(e5, bk[5].y, sy); sz = fmaf(e5, bk[5].z, sz); sw = fmaf(e5, bk[5].w, sw);
            sx = fmaf(e6, bk[6].x, sx); sy = fmaf(e6, bk[6].y, sy); sz = fmaf(e6, bk[6].z, sz); sw = fmaf(e6, bk[6].w, sw);
            sx = fmaf(e7, bk[7].x, sx); sy = fmaf(e7, bk[7].y, sy); sz = fmaf(e7, bk[7].z, sz); sw = fmaf(e7, bk[7].w, sw);
            accz[rr][0] = sx; accz[rr][1] = sy; accz[rr][2] = sz; accz[rr][3] = sw;
        }
    }

    // ---- stage z_q tile to LDS, then coalesced store (out layout [B][C][T])
#pragma unroll
    for (int rr = 0; rr < 4; ++rr)
        *(float4*)&ztile[r0g + rr][c0g] = make_float4(accz[rr][0], accz[rr][1], accz[rr][2], accz[rr][3]);
    __syncthreads();
    {
        float4* op = (float4*)(out + ((size_t)bb * CC + tid) * TT + t0);
        op[0] = make_float4(ztile[0][tid],  ztile[1][tid],  ztile[2][tid],  ztile[3][tid]);
        op[1] = make_float4(ztile[4][tid],  ztile[5][tid],  ztile[6][tid],  ztile[7][tid]);
        op[2] = make_float4(ztile[8][tid],  ztile[9][tid],  ztile[10][tid], ztile[11][tid]);
        op[3] = make_float4(ztile[12][tid], ztile[13][tid], ztile[14][tid], ztile[15][tid]);
    }
}

// -------- mean_prob reduction over per-block partials --------
__global__ void meanp_kernel(const float* __restrict__ part, float* __restrict__ out) {
    int k  = blockIdx.x * blockDim.x + threadIdx.x;   // 4 x 256 = 1024 k's
    int b0 = blockIdx.y * (NBLK / 16);
    float s = 0.f;
#pragma unroll 4
    for (int b = 0; b < NBLK / 16; ++b)
        s += part[(size_t)(b0 + b) * KK + k];
    atomicAdd(out + OUT_MEANPROB + k, s * (1.f / NN));
}

extern "C" void kernel_launch(void* const* d_in, const int* in_sizes, int n_in,
                              void* d_out, int out_size, void* d_ws, size_t ws_size,
                              hipStream_t stream) {
    const float* z    = (const float*)d_in[0];
    const float* book = (const float*)d_in[1];
    const float* lpq  = (const float*)d_in[2];
    const float* u    = (const float*)d_in[3];
    float* out   = (float*)d_out;
    float* enorm = (float*)d_ws;

    size_t need = (size_t)(KK + (size_t)NBLK * KK) * sizeof(float);
    float* part = (ws_size >= need) ? ((float*)d_ws + KK) : nullptr;

    prep_kernel<<<KK / 256, 256, 0, stream>>>(book, lpq, enorm, out);
    gvq_main<<<NBLK, 256, 0, stream>>>(z, book, lpq, u, enorm, out, part);
    if (part != nullptr)
        meanp_kernel<<<dim3(4, 16), 256, 0, stream>>>(part, out);
}